// Round 8
// baseline (1086.168 us; speedup 1.0000x reference)
//
#include <hip/hip_runtime.h>
#include <cstddef>
#include <cstdint>

#define T_LEN 512
#define O_DIM 4

typedef _Float16 f16x8 __attribute__((ext_vector_type(8)));
typedef _Float16 f16x4 __attribute__((ext_vector_type(4)));
typedef float    f32x4 __attribute__((ext_vector_type(4)));

#define MFMA(a, b, c) __builtin_amdgcn_mfma_f32_16x16x32_f16((a), (b), (c), 0, 0, 0)

__device__ __forceinline__ float sigm_f(float x) {
    return __builtin_amdgcn_rcpf(1.0f + __builtin_amdgcn_exp2f(x * -1.44269504f));
}
__device__ __forceinline__ float tanh_f(float x) {
    float e = __builtin_amdgcn_exp2f(x * 2.88539008f);
    return __builtin_fmaf(-2.0f, __builtin_amdgcn_rcpf(e + 1.0f), 1.0f);
}

// B-fragment for 16x16x32 f16 MFMA from a row-major [K x 64] fp32 matrix.
__device__ __forceinline__ f16x8 load_bt(const float* __restrict__ W, int k0, int n) {
    const int lane = threadIdx.x & 63;
    const float* p = W + (size_t)(k0 + ((lane >> 4) << 3)) * 64 + n;
    f16x8 r;
#pragma unroll
    for (int j = 0; j < 8; ++j) r[j] = (_Float16)p[(size_t)j * 64];
    return r;
}

// A-fragment from LDS state array [16][76] f16 (bank-spread stride, R5: the
// exact codegen that benched 393us).
__device__ __forceinline__ f16x8 ld_af(const _Float16* base, int kt) {
    const int lane = threadIdx.x & 63;
    const int m = lane & 15, q = lane >> 4;
    const _Float16* p = base + m * 76 + kt * 32 + q * 8;
    f16x4 lo = *(const f16x4*)(p);
    f16x4 hi = *(const f16x4*)(p + 4);
    f16x8 r;
    r[0] = lo[0]; r[1] = lo[1]; r[2] = lo[2]; r[3] = lo[3];
    r[4] = hi[0]; r[5] = hi[1]; r[6] = hi[2]; r[7] = hi[3];
    return r;
}

// ---- prep kernel: convert the 26 streamed weight fragments to f16 MFMA
// layout in workspace. Slot fs: ws[fs*2048 + w*512 + lane*8], 16B/lane.
// Same load_bt conversion as the resident path -> bitwise-identical values.
__global__ void anima_prep_86887188398421(
    const float* __restrict__ WfW, const float* __restrict__ WfI,
    const float* __restrict__ Wg_w, const float* __restrict__ Iz_w,
    const float* __restrict__ Ir_w, const float* __restrict__ Ih_w,
    const float* __restrict__ AfW, const float* __restrict__ AfA,
    const float* __restrict__ Ag_w, _Float16* __restrict__ ws)
{
    const int tid = threadIdx.x;
    const int w = tid >> 6, lane = tid & 63;
    const int n = w * 16 + (lane & 15);
    const int fs = blockIdx.x;
    const float* mat; int k0;
    switch (fs) {
        case 0:  mat = Iz_w; k0 = 128; break;  case 1:  mat = Iz_w; k0 = 160; break;
        case 2:  mat = Ir_w; k0 = 128; break;  case 3:  mat = Ir_w; k0 = 160; break;
        case 4:  mat = Ih_w; k0 = 128; break;  case 5:  mat = Ih_w; k0 = 160; break;
        case 6:  mat = AfA;  k0 = 0;   break;  case 7:  mat = AfA;  k0 = 32;  break;
        case 8:  mat = Iz_w; k0 = 0;   break;  case 9:  mat = Iz_w; k0 = 32;  break;
        case 10: mat = Ih_w; k0 = 0;   break;  case 11: mat = Ih_w; k0 = 32;  break;
        case 12: mat = WfW;  k0 = 0;   break;  case 13: mat = WfW;  k0 = 32;  break;
        case 14: mat = AfW;  k0 = 0;   break;  case 15: mat = AfW;  k0 = 32;  break;
        case 16: mat = Ag_w; k0 = 0;   break;  case 17: mat = Ag_w; k0 = 32;  break;
        case 18: mat = WfI;  k0 = 0;   break;  case 19: mat = WfI;  k0 = 32;  break;
        case 20: mat = Wg_w; k0 = 0;   break;  case 21: mat = Wg_w; k0 = 32;  break;
        case 22: mat = Iz_w; k0 = 64;  break;  case 23: mat = Iz_w; k0 = 96;  break;
        case 24: mat = Ir_w; k0 = 64;  break;  default: mat = Ir_w; k0 = 96;  break;
    }
    f16x8 v = load_bt(mat, k0, n);
    *(f16x8*)(ws + (size_t)fs * 2048 + w * 512 + lane * 8) = v;
}

// 2 rows/block, 512 blocks. R6/R7 post-mortem: with weights register-resident
// the unified VGPR+AGPR allocation is ~350/wave (compiler parks B-frags in
// AGPRs, invisible to VGPR_Count) -> pinned 1 wave/SIMD. R2 PROVED (256,2)
// does co-schedule 2 blocks/CU (21% occ, MfmaUtil 48%) when total <=256 —
// it only lost to spills because 350 regs of state were forced under the cap.
// THIS round removes the state instead of spilling it: the 26 NON-critical
// fragments stream from L2 (prep kernel wrote them to d_ws in MFMA layout),
// loaded one segment ahead inside each ds_read shadow (>=250cy before use
// >> ~200cy L2 latency; barrier vmcnt drains are free). 12 critical frags +
// phi stay resident (56 regs). Estimated total ~235 <= 256 -> no spills ->
// 2 waves/SIMD -> MFMA and VALU pipes of the two blocks overlap (m114).
// An empty asm on the ws pointer each iteration blocks LICM from re-hoisting
// the 26 loads into residency (which would recreate R2's spill disaster).
__global__ __launch_bounds__(256, 2) void ANIMAZeroExact_86887188398421_kernel(
    const float* __restrict__ x,
    const float* __restrict__ Wenc_w, const float* __restrict__ Wenc_b,
    const float* __restrict__ WfW, const float* __restrict__ WfI, const float* __restrict__ WfA,
    const float* __restrict__ Wg_w, const float* __restrict__ Wg_b,
    const float* __restrict__ Iz_w, const float* __restrict__ Iz_b,
    const float* __restrict__ Ir_w, const float* __restrict__ Ir_b,
    const float* __restrict__ Ih_w, const float* __restrict__ Ih_b,
    const float* __restrict__ AfW, const float* __restrict__ AfI, const float* __restrict__ AfA,
    const float* __restrict__ Ag_w, const float* __restrict__ Ag_b,
    const float* __restrict__ phi_w, const float* __restrict__ phi_b,
    const _Float16* __restrict__ ws,
    float* __restrict__ out)
{
    __shared__ __align__(16) _Float16 Wl[16][76];
    __shared__ __align__(16) _Float16 Il[16][76];
    __shared__ __align__(16) _Float16 Al[16][76];
    __shared__ __align__(16) _Float16 Rl[16][76];
    __shared__ __align__(16) _Float16 Ahist[16][4][72];  // [t&15][tilerow][dim] (rows 2,3 dup)
    __shared__ __align__(16) float xbig[2][520];         // 64-step x chunk, 2 rows
    __shared__ __align__(16) float actb[2][64][4];       // 64-step action buffer

    const int tid  = threadIdx.x;
    const int w    = tid >> 6;
    const int lane = tid & 63;
    const int q    = lane >> 4;
    const int qb   = q & 1;          // real batch row this lane mirrors
    const int c    = lane & 15;
    const int n    = w * 16 + c;
    const int r0   = blockIdx.x * 2;

    // x-prefetch / flush lane mapping (one float4 per thread)
    const int prow = tid >> 7;           // 0..1
    const int pidx = tid & 127;
    const int psu  = pidx >> 1;          // 0..63 slot
    const int phl  = (pidx & 1) * 4;     // float4 half offset
    const int frow = tid >> 6;           // flush row (valid < 2)
    const int fs   = tid & 63;           // flush slot

    for (int i = tid; i < 16 * 76; i += 256) {
        (&Wl[0][0])[i] = (_Float16)0.0f; (&Il[0][0])[i] = (_Float16)0.0f;
        (&Al[0][0])[i] = (_Float16)0.0f; (&Rl[0][0])[i] = (_Float16)0.0f;
    }

    // ---- resident CRITICAL weight fragments only (12 + phi = 56 regs) ----
    f16x8 rS14, rS15, rG12, rG13, rRB0, rRB1, rHB2, rHB3, rAB2, rAB3, rAG2, rAG3, phiB[2];
    rS14 = load_bt(WfA, 0, n);   rS15 = load_bt(WfA, 32, n);     // seg1 crit (W_in A-term)
    rG12 = load_bt(Wg_w, 64, n); rG13 = load_bt(Wg_w, 96, n);    // seg1 crit (Wg A-half)
    rRB0 = load_bt(Ir_w, 0, n);  rRB1 = load_bt(Ir_w, 32, n);    // seg2 crit (r W-term)
    rHB2 = load_bt(Ih_w, 64, n); rHB3 = load_bt(Ih_w, 96, n);    // seg3 crit (h rI-term)
    rAB2 = load_bt(AfI, 0, n);   rAB3 = load_bt(AfI, 32, n);     // seg4 crit (A I-term)
    rAG2 = load_bt(Ag_w, 64, n); rAG3 = load_bt(Ag_w, 96, n);    // seg4 crit (Ag I-half)
#pragma unroll
    for (int kt = 0; kt < 2; ++kt)
#pragma unroll
        for (int j = 0; j < 8; ++j) {
            int k = kt * 32 + q * 8 + j;
            phiB[kt][j] = (c < O_DIM) ? (_Float16)phi_w[k * O_DIM + c] : (_Float16)0.0f;
        }

    float We[8];
#pragma unroll
    for (int j = 0; j < 8; ++j) We[j] = Wenc_w[j * 64 + n];

    const float bias_g  = Wg_b[n],  bias_z = Iz_b[n], bias_r = Ir_b[n];
    const float bias_h  = Ih_b[n],  bias_ag = Ag_b[n], bias_e = Wenc_b[n];
    const float bias_p  = (c < O_DIM) ? phi_b[c] : 0.0f;

    f32x4 zero4 = {0.f, 0.f, 0.f, 0.f};

    // streamed-fragment base pointer (per wave+lane); made opaque each
    // iteration so LICM cannot hoist the 26 loads into residency.
    const _Float16* wfb = ws + w * 512 + lane * 8;
#define LDW(slot) (*(const f16x8*)(wfb + (size_t)(slot) * 2048))

    // prologue: stage x-chunk slots 0..63 = x(1..64), one float4 per thread
    {
        const float* xg = x + (size_t)(r0 + prow) * (T_LEN * 8) + (1 + psu) * 8 + phl;
        *(float4*)(&xbig[prow][psu * 8 + phl]) = *(const float4*)(xg);
    }
    float xt;
    {
        const float* xg = x + (size_t)(r0 + qb) * (T_LEN * 8);
        float4 a = *(const float4*)(xg);
        float4 b = *(const float4*)(xg + 4);
        float d = bias_e;
        d = __builtin_fmaf(a.x, We[0], d); d = __builtin_fmaf(a.y, We[1], d);
        d = __builtin_fmaf(a.z, We[2], d); d = __builtin_fmaf(a.w, We[3], d);
        d = __builtin_fmaf(b.x, We[4], d); d = __builtin_fmaf(b.y, We[5], d);
        d = __builtin_fmaf(b.z, We[6], d); d = __builtin_fmaf(b.w, We[7], d);
        xt = tanh_f(d);
    }

    // loop-carried accumulators (all zero-init = value for states(-1)=0)
    f32x4 w_a = zero4, w_b = zero4, g_a = zero4, g_b = zero4;
    f32x4 zp_a = zero4, zp_c = zero4, rp_a = zero4, rp_c = zero4;
    f32x4 hp_a, hp_c, ap_a, ap_c, ag_a, ag_c;
    float Iv = 0.f;
    f16x8 nW0, nW1;

    // loop-carried streamed frags for seg1-late (z/r A-terms), first load here
    f16x8 sZB4 = LDW(0), sZB5 = LDW(1), sRB4 = LDW(2), sRB5 = LDW(3);

    __syncthreads();

#pragma unroll 1
    for (int t = 0; t < T_LEN; ++t) {
        const bool fl16 = ((t & 15) == 0) && (t > 0);
        const bool fl64 = ((t & 63) == 0) && (t > 0);

        // block LICM on the streamed loads (wfb "changes" each iteration)
        asm volatile("" : "+v"(wfb));

        // ============ seg1: W_new ============
        f16x8 sA0 = ld_af(&Al[0][0], 0), sA1 = ld_af(&Al[0][0], 1);
        // issue seg2's streamed frags inside the ds_read shadow
        f16x8 sHB4 = LDW(4),  sHB5 = LDW(5),  sAB4 = LDW(6),  sAB5 = LDW(7);
        f16x8 sZB0 = LDW(8),  sZB1 = LDW(9),  sHB0 = LDW(10), sHB1 = LDW(11);
        f16x8 sS10 = LDW(12), sS11 = LDW(13);
        float4 xra = {0,0,0,0};
        if (fl64) {  // uniform 64-step x prefetch
            int off = (t + 1 + psu) * 8;
            if (off > T_LEN * 8 - 8) off = T_LEN * 8 - 8;
            xra = *(const float4*)(x + (size_t)(r0 + prow) * (T_LEN * 8) + off + phl);
        }
        // critical: w/g accumulators last touched in prev seg4-late (1 barrier ago)
        w_a = MFMA(sA0, rS14, w_a);  w_b = MFMA(sA1, rS15, w_b);
        g_a = MFMA(sA0, rG12, g_a);  g_b = MFMA(sA1, rG13, g_b);
        {
            float wn = tanh_f(xt + w_a[0] + w_b[0]) * sigm_f(g_a[0] + g_b[0] + bias_g);
            Wl[4 * q][n] = (_Float16)wn;
        }
        // late fillers: z/r A-terms (loaded in prev seg4)
        zp_a = MFMA(sA0, sZB4, zp_a);  zp_c = MFMA(sA1, sZB5, zp_c);
        rp_a = MFMA(sA0, sRB4, rp_a);  rp_c = MFMA(sA1, sRB5, rp_c);
        __syncthreads();  // alpha

        // ============ seg2: r*I ============
        nW0 = ld_af(&Wl[0][0], 0); nW1 = ld_af(&Wl[0][0], 1);
        // issue seg3's streamed frags inside the ds_read shadow
        f16x8 sAB0 = LDW(14), sAB1 = LDW(15), sAG0 = LDW(16), sAG1 = LDW(17);
        // early fillers (sA-based, fresh accumulators) cover the nW read
        hp_a = MFMA(sA0, sHB4, zero4); hp_c = MFMA(sA1, sHB5, zero4);
        ap_a = MFMA(sA0, sAB4, zero4); ap_c = MFMA(sA1, sAB5, zero4);
        if (fl16) {
            // batched phi: actions for steps t-16..t-1 from Ahist, ALL waves
            const _Float16* ah = &Ahist[0][0][0];
            const int hw = (4 * w + (c >> 2)) * 288 + (c & 3) * 72 + 8 * q;
            f16x8 a0 = *(const f16x8*)(ah + hw);
            f16x8 a1 = *(const f16x8*)(ah + hw + 32);
            f32x4 act = MFMA(a0, phiB[0], zero4);
            act = MFMA(a1, phiB[1], act);
            if (c < O_DIM) {
                const int slot = (t - 16 + 4 * w + q) & 63;
#pragma unroll
                for (int rg = 0; rg < 2; ++rg)
                    actb[rg][slot][c] = act[rg] + bias_p;
            }
        }
        // critical: rp last touched seg1-late (1 barrier ago)
        rp_a = MFMA(nW0, rRB0, rp_a);  rp_c = MFMA(nW1, rRB1, rp_c);
        {
            float rv = sigm_f(rp_a[0] + rp_c[0] + bias_r);
            Rl[4 * q][n] = (_Float16)(rv * Iv);
        }
        // late fillers (nW-based): grind through beta into seg3's read window
        zp_a = MFMA(nW0, sZB0, zp_a);  zp_c = MFMA(nW1, sZB1, zp_c);
        hp_a = MFMA(nW0, sHB0, hp_a);  hp_c = MFMA(nW1, sHB1, hp_c);
        w_a  = MFMA(nW0, sS10, zero4); w_b = MFMA(nW1, sS11, zero4);
        if (fl64)
            *(float4*)(&xbig[prow][psu * 8 + phl]) = xra;
        __syncthreads();  // beta

        // ============ seg3: I_new ============
        f16x8 hR0 = ld_af(&Rl[0][0], 0), hR1 = ld_af(&Rl[0][0], 1);
        // issue seg4's streamed frags inside the ds_read shadow
        f16x8 sS12 = LDW(18), sS13 = LDW(19), sG10 = LDW(20), sG11 = LDW(21);
        f16x8 sZB2 = LDW(22), sZB3 = LDW(23), sRB2 = LDW(24), sRB3 = LDW(25);
        const float* xs = &xbig[qb][(t & 63) * 8];
        float4 qa = *(const float4*)xs;
        float4 qb4 = *(const float4*)(xs + 4);
        // early fillers (nW-based) + VALU cover the hR read
        ap_a = MFMA(nW0, sAB0, ap_a);  ap_c = MFMA(nW1, sAB1, ap_c);
        float zv = sigm_f(zp_a[0] + zp_c[0] + bias_z);
        float xtn;
        {
            float d = bias_e;
            d = __builtin_fmaf(qa.x, We[0], d); d = __builtin_fmaf(qa.y, We[1], d);
            d = __builtin_fmaf(qa.z, We[2], d); d = __builtin_fmaf(qa.w, We[3], d);
            d = __builtin_fmaf(qb4.x, We[4], d); d = __builtin_fmaf(qb4.y, We[5], d);
            d = __builtin_fmaf(qb4.z, We[6], d); d = __builtin_fmaf(qb4.w, We[7], d);
            xtn = tanh_f(d);
        }
        if (fl64 && tid < 128) {  // 64-step action flush (rows 0..1)
            float4 av = *(const float4*)(&actb[frow][fs][0]);
            *(float4*)(out + (size_t)(r0 + frow) * (T_LEN * O_DIM) + (t - 64 + fs) * 4) = av;
        }
        // critical: hp last touched seg2-late (1 barrier ago)
        hp_a = MFMA(hR0, rHB2, hp_a);  hp_c = MFMA(hR1, rHB3, hp_c);
        {
            float hv = tanh_f(hp_a[0] + hp_c[0] + bias_h);
            Iv = __builtin_fmaf(zv, hv - Iv, Iv);
            Il[4 * q][n] = (_Float16)Iv;
        }
        // late fillers (nW-based, fresh): grind through gamma into seg4's read window
        ag_a = MFMA(nW0, sAG0, zero4); ag_c = MFMA(nW1, sAG1, zero4);
        __syncthreads();  // gamma

        // ============ seg4: A_new ============
        f16x8 nI0 = ld_af(&Il[0][0], 0), nI1 = ld_af(&Il[0][0], 1);
        // issue next-seg1's streamed frags inside the ds_read shadow
        sZB4 = LDW(0); sZB5 = LDW(1); sRB4 = LDW(2); sRB5 = LDW(3);
        // critical: ap last touched seg3-early, ag seg3-late (completed by now)
        ap_a = MFMA(nI0, rAB2, ap_a);  ap_c = MFMA(nI1, rAB3, ap_c);
        ag_a = MFMA(nI0, rAG2, ag_a);  ag_c = MFMA(nI1, rAG3, ag_c);
        {
            float av = tanh_f(ap_a[0] + ap_c[0]) * sigm_f(ag_a[0] + ag_c[0] + bias_ag);
            Al[4 * q][n] = (_Float16)av;
            Ahist[t & 15][q][n] = (_Float16)av;   // append to phi history (same cvt)
        }
        // late fillers (nI-based): next step's W/Wg/z/r I-terms; grind through delta
        w_a = MFMA(nI0, sS12, w_a);   w_b = MFMA(nI1, sS13, w_b);
        g_a = MFMA(nI0, sG10, zero4); g_b = MFMA(nI1, sG11, zero4);
        zp_a = MFMA(nI0, sZB2, zero4); zp_c = MFMA(nI1, sZB3, zero4);
        rp_a = MFMA(nI0, sRB2, zero4); rp_c = MFMA(nI1, sRB3, zero4);
        xt = xtn;
        __syncthreads();  // delta
    }

    // epilogue: final phi batch (steps 496..511) + final flush (448..511)
    {
        const _Float16* ah = &Ahist[0][0][0];
        const int hw = (4 * w + (c >> 2)) * 288 + (c & 3) * 72 + 8 * q;
        f16x8 a0 = *(const f16x8*)(ah + hw);
        f16x8 a1 = *(const f16x8*)(ah + hw + 32);
        f32x4 act = MFMA(a0, phiB[0], zero4);
        act = MFMA(a1, phiB[1], act);
        if (c < O_DIM) {
            const int slot = 48 + 4 * w + q;   // (512-16+4w+q)&63
#pragma unroll
            for (int rg = 0; rg < 2; ++rg)
                actb[rg][slot][c] = act[rg] + bias_p;
        }
        __syncthreads();
        if (tid < 128) {
            float4 av = *(const float4*)(&actb[frow][fs][0]);
            *(float4*)(out + (size_t)(r0 + frow) * (T_LEN * O_DIM) + (448 + fs) * 4) = av;
        }
    }
#undef LDW
}

extern "C" void kernel_launch(void* const* d_in, const int* in_sizes, int n_in,
                              void* d_out, int out_size, void* d_ws, size_t ws_size,
                              hipStream_t stream) {
    // pass 1: convert the 26 streamed weight fragments into MFMA layout in ws
    anima_prep_86887188398421<<<dim3(26), dim3(256), 0, stream>>>(
        (const float*)d_in[3],  (const float*)d_in[4],
        (const float*)d_in[6],  (const float*)d_in[8],
        (const float*)d_in[10], (const float*)d_in[12],
        (const float*)d_in[14], (const float*)d_in[16],
        (const float*)d_in[17], (_Float16*)d_ws);
    // pass 2: recurrence
    ANIMAZeroExact_86887188398421_kernel<<<dim3(512), dim3(256), 0, stream>>>(
        (const float*)d_in[0],
        (const float*)d_in[1],  (const float*)d_in[2],
        (const float*)d_in[3],  (const float*)d_in[4],  (const float*)d_in[5],
        (const float*)d_in[6],  (const float*)d_in[7],
        (const float*)d_in[8],  (const float*)d_in[9],
        (const float*)d_in[10], (const float*)d_in[11],
        (const float*)d_in[12], (const float*)d_in[13],
        (const float*)d_in[14], (const float*)d_in[15], (const float*)d_in[16],
        (const float*)d_in[17], (const float*)d_in[18],
        (const float*)d_in[19], (const float*)d_in[20],
        (const _Float16*)d_ws,
        (float*)d_out);
}

// Round 9
// 456.822 us; speedup vs baseline: 2.3777x; 2.3777x over previous
//
#include <hip/hip_runtime.h>
#include <cstddef>
#include <cstdint>

#define T_LEN 512
#define O_DIM 4

typedef _Float16 f16x8 __attribute__((ext_vector_type(8)));
typedef _Float16 f16x4 __attribute__((ext_vector_type(4)));
typedef float    f32x4 __attribute__((ext_vector_type(4)));

#define MFMA(a, b, c) __builtin_amdgcn_mfma_f32_16x16x32_f16((a), (b), (c), 0, 0, 0)

__device__ __forceinline__ float sigm_f(float x) {
    return __builtin_amdgcn_rcpf(1.0f + __builtin_amdgcn_exp2f(x * -1.44269504f));
}
__device__ __forceinline__ float tanh_f(float x) {
    float e = __builtin_amdgcn_exp2f(x * 2.88539008f);
    return __builtin_fmaf(-2.0f, __builtin_amdgcn_rcpf(e + 1.0f), 1.0f);
}

// B-fragment for 16x16x32 f16 MFMA from a row-major [K x 64] fp32 matrix.
__device__ __forceinline__ f16x8 load_bt(const float* __restrict__ W, int k0, int n) {
    const int lane = threadIdx.x & 63;
    const float* p = W + (size_t)(k0 + ((lane >> 4) << 3)) * 64 + n;
    f16x8 r;
#pragma unroll
    for (int j = 0; j < 8; ++j) r[j] = (_Float16)p[(size_t)j * 64];
    return r;
}

// A-fragment from LDS state array [16][76] f16.
// Stride 76 f16 = 152 B = 19*8 B: 8B-aligned (so b64 reads), and the dword
// bank base (6m + 16kt + 4q + 2h) mod 32 spreads the 16 m-rows over 16
// DISTINCT banks (~2-way worst case, free per m136). The old [16][72]
// layout put every lane's b128 base on a bank = 0 mod 4 (8 groups for 64
// lanes, ~8-way) -- measured 1.7e7 conflict cycles = ~2.7 cy per LDS op.
__device__ __forceinline__ f16x8 ld_af(const _Float16* base, int kt) {
    const int lane = threadIdx.x & 63;
    const int m = lane & 15, q = lane >> 4;
    const _Float16* p = base + m * 76 + kt * 32 + q * 8;
    f16x4 lo = *(const f16x4*)(p);
    f16x4 hi = *(const f16x4*)(p + 4);
    f16x8 r;
    r[0] = lo[0]; r[1] = lo[1]; r[2] = lo[2]; r[3] = lo[3];
    r[4] = hi[0]; r[5] = hi[1]; r[6] = hi[2]; r[7] = hi[3];
    return r;
}

// 256 threads = 4 waves, 4 valid batch rows at tile rows {0,4,8,12}.
// FINAL (R8 ledger): this is the session's best kernel (393us). Closed doors,
// each counter-explained:
//  - cross-block co-residency: (256,2) cap -> spills (R2); natural alloc ->
//    >256 total regs on the unified VGPR+AGPR file (R3/R6); streaming weights
//    from L2 -> vmcnt-serialized at 104 VGPRs (R8, 2.7x loss).
//  - in-wave dual-chain ILP: wave is issue-bound per segment, adding a 2nd
//    chain adds issue, doesn't fill latency (R4).
//  - LDS bank conflicts: eliminated 12.6x (this [76] layout), time-neutral ->
//    conflicts were hidden (R5).
//  - VALU trimming / schedule touches: regress the locally-optimal schedule
//    (R7: -8% despite VALUBusy dropping as predicted).
// Structure: serial 4-exchange recurrence (W->r->I->A, each through a matmul,
// algorithmically minimal), 1 wave/SIMD, serial issue ~1307 cy/step
// (MFMA 644 + VALU 663) + ~530 cy unfillable dependency/barrier stall.
// Scheduling discipline per segment (tuned baseline):
//   - EARLY fillers (operands from a PREVIOUS segment's read) cover this
//     segment's ds_read latency,
//   - critical MFMAs chain only onto accumulators whose last write completed
//     >=1 barrier earlier,
//   - LATE fillers issue after the critical publish and grind through the
//     barrier into the NEXT segment's read window.
// Retained: batched phi via Ahist; 64-step uniform x prefetch; 64-step
// buffered action flush.
__global__ __launch_bounds__(256, 1) void ANIMAZeroExact_86887188398421_kernel(
    const float* __restrict__ x,
    const float* __restrict__ Wenc_w, const float* __restrict__ Wenc_b,
    const float* __restrict__ WfW, const float* __restrict__ WfI, const float* __restrict__ WfA,
    const float* __restrict__ Wg_w, const float* __restrict__ Wg_b,
    const float* __restrict__ Iz_w, const float* __restrict__ Iz_b,
    const float* __restrict__ Ir_w, const float* __restrict__ Ir_b,
    const float* __restrict__ Ih_w, const float* __restrict__ Ih_b,
    const float* __restrict__ AfW, const float* __restrict__ AfI, const float* __restrict__ AfA,
    const float* __restrict__ Ag_w, const float* __restrict__ Ag_b,
    const float* __restrict__ phi_w, const float* __restrict__ phi_b,
    float* __restrict__ out)
{
    __shared__ __align__(16) _Float16 Wl[16][76];
    __shared__ __align__(16) _Float16 Il[16][76];
    __shared__ __align__(16) _Float16 Al[16][76];
    __shared__ __align__(16) _Float16 Rl[16][76];
    __shared__ __align__(16) _Float16 Ahist[16][4][72];  // [t&15][rowidx][dim]; 16B-aligned rows, b128 ok (rare)
    __shared__ __align__(16) float xbig[4][520];         // 64-step x chunk, padded stride
    __shared__ __align__(16) float actb[4][64][4];       // 64-step action buffer

    const int tid  = threadIdx.x;
    const int w    = tid >> 6;
    const int lane = tid & 63;
    const int q    = lane >> 4;
    const int c    = lane & 15;
    const int n    = w * 16 + c;
    const int r0   = blockIdx.x * 4;

    const int prow = tid >> 6;       // x prefetch: 4 rows x 64 slots, 2 float4/thread
    const int psu  = tid & 63;
    const int frow = tid >> 6;       // flush: 4 rows x 64 slots
    const int fs   = tid & 63;

    for (int i = tid; i < 16 * 76; i += 256) {
        (&Wl[0][0])[i] = (_Float16)0.0f; (&Il[0][0])[i] = (_Float16)0.0f;
        (&Al[0][0])[i] = (_Float16)0.0f; (&Rl[0][0])[i] = (_Float16)0.0f;
    }

    // ---- resident weight B-fragments ----
    f16x8 S1B[6], G1B[4], ZB[6], RB[6], HB[6], AB[6], AGB[4], phiB[2];
#pragma unroll
    for (int j = 0; j < 2; ++j) {
        S1B[j] = load_bt(WfW, 32 * j, n);  S1B[2 + j] = load_bt(WfI, 32 * j, n);  S1B[4 + j] = load_bt(WfA, 32 * j, n);
        AB[j]  = load_bt(AfW, 32 * j, n);  AB[2 + j]  = load_bt(AfI, 32 * j, n);  AB[4 + j]  = load_bt(AfA, 32 * j, n);
    }
#pragma unroll
    for (int j = 0; j < 4; ++j) { G1B[j] = load_bt(Wg_w, 32 * j, n); AGB[j] = load_bt(Ag_w, 32 * j, n); }
#pragma unroll
    for (int j = 0; j < 6; ++j) { ZB[j] = load_bt(Iz_w, 32 * j, n); RB[j] = load_bt(Ir_w, 32 * j, n); HB[j] = load_bt(Ih_w, 32 * j, n); }
    // phi fragment in ALL waves (batched phi); cols >= O_DIM zeroed
#pragma unroll
    for (int kt = 0; kt < 2; ++kt)
#pragma unroll
        for (int j = 0; j < 8; ++j) {
            int k = kt * 32 + q * 8 + j;
            phiB[kt][j] = (c < O_DIM) ? (_Float16)phi_w[k * O_DIM + c] : (_Float16)0.0f;
        }

    float We[8];
#pragma unroll
    for (int j = 0; j < 8; ++j) We[j] = Wenc_w[j * 64 + n];

    const float bias_g  = Wg_b[n],  bias_z = Iz_b[n], bias_r = Ir_b[n];
    const float bias_h  = Ih_b[n],  bias_ag = Ag_b[n], bias_e = Wenc_b[n];
    const float bias_p  = (c < O_DIM) ? phi_b[c] : 0.0f;

    f32x4 zero4 = {0.f, 0.f, 0.f, 0.f};

    // prologue: stage x-chunk slots 0..63 = x(1..64), all threads uniform
    {
        const float* xg = x + (size_t)(r0 + prow) * (T_LEN * 8) + (1 + psu) * 8;
        float4 a = *(const float4*)(xg);
        float4 b = *(const float4*)(xg + 4);
        float* d = &xbig[prow][psu * 8];
        *(float4*)d = a; *(float4*)(d + 4) = b;
    }
    float xt;
    {
        const float* xg = x + (size_t)(r0 + q) * (T_LEN * 8);
        float4 a = *(const float4*)(xg);
        float4 b = *(const float4*)(xg + 4);
        float d = bias_e;
        d = __builtin_fmaf(a.x, We[0], d); d = __builtin_fmaf(a.y, We[1], d);
        d = __builtin_fmaf(a.z, We[2], d); d = __builtin_fmaf(a.w, We[3], d);
        d = __builtin_fmaf(b.x, We[4], d); d = __builtin_fmaf(b.y, We[5], d);
        d = __builtin_fmaf(b.z, We[6], d); d = __builtin_fmaf(b.w, We[7], d);
        xt = tanh_f(d);
    }

    // loop-carried accumulators (all zero-init = value for states(-1)=0)
    f32x4 w_a = zero4, w_b = zero4, g_a = zero4, g_b = zero4;
    f32x4 zp_a = zero4, zp_c = zero4, rp_a = zero4, rp_c = zero4;
    f32x4 hp_a, hp_c, ap_a, ap_c, ag_a, ag_c;
    float Iv = 0.f;
    f16x8 nW0, nW1;

    __syncthreads();

#pragma unroll 1
    for (int t = 0; t < T_LEN; ++t) {
        const bool fl16 = ((t & 15) == 0) && (t > 0);
        const bool fl64 = ((t & 63) == 0) && (t > 0);

        // ============ seg1: W_new ============
        // read window covered by prev seg4's late fillers still in the pipe
        f16x8 sA0 = ld_af(&Al[0][0], 0), sA1 = ld_af(&Al[0][0], 1);
        float4 xra = {0,0,0,0}, xrb = {0,0,0,0};
        if (fl64) {  // uniform 64-step x prefetch (all 256 threads)
            int off = (t + 1 + psu) * 8;
            if (off > T_LEN * 8 - 8) off = T_LEN * 8 - 8;
            const float* xg = x + (size_t)(r0 + prow) * (T_LEN * 8) + off;
            xra = *(const float4*)(xg); xrb = *(const float4*)(xg + 4);
        }
        // critical: w/g accumulators last touched in prev seg4-late (1 barrier ago)
        w_a = MFMA(sA0, S1B[4], w_a);  w_b = MFMA(sA1, S1B[5], w_b);
        g_a = MFMA(sA0, G1B[2], g_a);  g_b = MFMA(sA1, G1B[3], g_b);
        {
            float wn = tanh_f(xt + w_a[0] + w_b[0]) * sigm_f(g_a[0] + g_b[0] + bias_g);
            Wl[4 * q][n] = (_Float16)wn;
        }
        // late fillers: z/r A-terms (r's A-term must be 1 barrier before seg2's critical r)
        zp_a = MFMA(sA0, ZB[4], zp_a);  zp_c = MFMA(sA1, ZB[5], zp_c);
        rp_a = MFMA(sA0, RB[4], rp_a);  rp_c = MFMA(sA1, RB[5], rp_c);
        __syncthreads();  // alpha

        // ============ seg2: r*I ============
        nW0 = ld_af(&Wl[0][0], 0); nW1 = ld_af(&Wl[0][0], 1);
        // early fillers (sA-based, fresh accumulators) cover the nW read
        hp_a = MFMA(sA0, HB[4], zero4); hp_c = MFMA(sA1, HB[5], zero4);
        ap_a = MFMA(sA0, AB[4], zero4); ap_c = MFMA(sA1, AB[5], zero4);
        if (fl16) {
            // batched phi: actions for steps t-16..t-1 from Ahist, ALL waves,
            // wave w covers sub-steps 4w..4w+3. Fragment rows m -> (su=4w+(m>>2),
            // rowidx=m&3); bitwise-identical dot to the per-step scheme.
            const _Float16* ah = &Ahist[0][0][0];
            const int hw = (4 * w + (c >> 2)) * 288 + (c & 3) * 72 + 8 * q;
            f16x8 a0 = *(const f16x8*)(ah + hw);
            f16x8 a1 = *(const f16x8*)(ah + hw + 32);
            f32x4 act = MFMA(a0, phiB[0], zero4);
            act = MFMA(a1, phiB[1], act);
            if (c < O_DIM) {
                const int slot = (t - 16 + 4 * w + q) & 63;
#pragma unroll
                for (int rg = 0; rg < 4; ++rg)
                    actb[rg][slot][c] = act[rg] + bias_p;
            }
        }
        // critical: rp last touched seg1-late (1 barrier ago)
        rp_a = MFMA(nW0, RB[0], rp_a);  rp_c = MFMA(nW1, RB[1], rp_c);
        {
            float rv = sigm_f(rp_a[0] + rp_c[0] + bias_r);
            Rl[4 * q][n] = (_Float16)(rv * Iv);
        }
        // late fillers (nW-based): grind through beta into seg3's read window
        zp_a = MFMA(nW0, ZB[0], zp_a);  zp_c = MFMA(nW1, ZB[1], zp_c);
        hp_a = MFMA(nW0, HB[0], hp_a);  hp_c = MFMA(nW1, HB[1], hp_c);
        w_a  = MFMA(nW0, S1B[0], zero4); w_b = MFMA(nW1, S1B[1], zero4);
        if (fl64) {
            float* d = &xbig[prow][psu * 8];
            *(float4*)d = xra; *(float4*)(d + 4) = xrb;
        }
        __syncthreads();  // beta

        // ============ seg3: I_new ============
        f16x8 hR0 = ld_af(&Rl[0][0], 0), hR1 = ld_af(&Rl[0][0], 1);
        const float* xs = &xbig[q][(t & 63) * 8];
        float4 qa = *(const float4*)xs;
        float4 qb = *(const float4*)(xs + 4);
        // early fillers (nW-based) + VALU cover the hR read
        ap_a = MFMA(nW0, AB[0], ap_a);  ap_c = MFMA(nW1, AB[1], ap_c);
        float zv = sigm_f(zp_a[0] + zp_c[0] + bias_z);
        float xtn;
        {
            float d = bias_e;
            d = __builtin_fmaf(qa.x, We[0], d); d = __builtin_fmaf(qa.y, We[1], d);
            d = __builtin_fmaf(qa.z, We[2], d); d = __builtin_fmaf(qa.w, We[3], d);
            d = __builtin_fmaf(qb.x, We[4], d); d = __builtin_fmaf(qb.y, We[5], d);
            d = __builtin_fmaf(qb.z, We[6], d); d = __builtin_fmaf(qb.w, We[7], d);
            xtn = tanh_f(d);
        }
        if (fl64) {  // uniform 64-step action flush (reads last seg's actb after beta)
            float4 av = *(const float4*)(&actb[frow][fs][0]);
            *(float4*)(out + (size_t)(r0 + frow) * (T_LEN * O_DIM) + (t - 64 + fs) * 4) = av;
        }
        // critical: hp last touched seg2-late (1 barrier ago)
        hp_a = MFMA(hR0, HB[2], hp_a);  hp_c = MFMA(hR1, HB[3], hp_c);
        {
            float hv = tanh_f(hp_a[0] + hp_c[0] + bias_h);
            Iv = __builtin_fmaf(zv, hv - Iv, Iv);
            Il[4 * q][n] = (_Float16)Iv;
        }
        // late fillers (nW-based, fresh): grind through gamma into seg4's read window
        ag_a = MFMA(nW0, AGB[0], zero4); ag_c = MFMA(nW1, AGB[1], zero4);
        __syncthreads();  // gamma

        // ============ seg4: A_new ============
        f16x8 nI0 = ld_af(&Il[0][0], 0), nI1 = ld_af(&Il[0][0], 1);
        // critical: ap last touched seg3-early, ag seg3-late (completed by now)
        ap_a = MFMA(nI0, AB[2], ap_a);  ap_c = MFMA(nI1, AB[3], ap_c);
        ag_a = MFMA(nI0, AGB[2], ag_a); ag_c = MFMA(nI1, AGB[3], ag_c);
        {
            float av = tanh_f(ap_a[0] + ap_c[0]) * sigm_f(ag_a[0] + ag_c[0] + bias_ag);
            Al[4 * q][n] = (_Float16)av;
            Ahist[t & 15][q][n] = (_Float16)av;   // append to phi history (same cvt)
        }
        // late fillers (nI-based): next step's W/Wg/z/r I-terms; grind through delta
        // into seg1's read window
        w_a = MFMA(nI0, S1B[2], w_a);   w_b = MFMA(nI1, S1B[3], w_b);
        g_a = MFMA(nI0, G1B[0], zero4); g_b = MFMA(nI1, G1B[1], zero4);
        zp_a = MFMA(nI0, ZB[2], zero4); zp_c = MFMA(nI1, ZB[3], zero4);
        rp_a = MFMA(nI0, RB[2], zero4); rp_c = MFMA(nI1, RB[3], zero4);
        xt = xtn;
        __syncthreads();  // delta
    }

    // epilogue: final phi batch (steps 496..511) + final flush (448..511)
    {
        const _Float16* ah = &Ahist[0][0][0];
        const int hw = (4 * w + (c >> 2)) * 288 + (c & 3) * 72 + 8 * q;
        f16x8 a0 = *(const f16x8*)(ah + hw);
        f16x8 a1 = *(const f16x8*)(ah + hw + 32);
        f32x4 act = MFMA(a0, phiB[0], zero4);
        act = MFMA(a1, phiB[1], act);
        if (c < O_DIM) {
            const int slot = 48 + 4 * w + q;   // (512-16+4w+q)&63
#pragma unroll
            for (int rg = 0; rg < 4; ++rg)
                actb[rg][slot][c] = act[rg] + bias_p;
        }
        __syncthreads();
        {
            float4 av = *(const float4*)(&actb[frow][fs][0]);
            *(float4*)(out + (size_t)(r0 + frow) * (T_LEN * O_DIM) + (448 + fs) * 4) = av;
        }
    }
}

extern "C" void kernel_launch(void* const* d_in, const int* in_sizes, int n_in,
                              void* d_out, int out_size, void* d_ws, size_t ws_size,
                              hipStream_t stream) {
    ANIMAZeroExact_86887188398421_kernel<<<dim3(256), dim3(256), 0, stream>>>(
        (const float*)d_in[0],
        (const float*)d_in[1],  (const float*)d_in[2],
        (const float*)d_in[3],  (const float*)d_in[4],  (const float*)d_in[5],
        (const float*)d_in[6],  (const float*)d_in[7],
        (const float*)d_in[8],  (const float*)d_in[9],
        (const float*)d_in[10], (const float*)d_in[11],
        (const float*)d_in[12], (const float*)d_in[13],
        (const float*)d_in[14], (const float*)d_in[15], (const float*)d_in[16],
        (const float*)d_in[17], (const float*)d_in[18],
        (const float*)d_in[19], (const float*)d_in[20],
        (float*)d_out);
}